// Round 2
// baseline (106.044 us; speedup 1.0000x reference)
//
#include <hip/hip_runtime.h>
#include <hip/hip_cooperative_groups.h>

namespace cg = cooperative_groups;

// CenterLoss: x [B=4096, D=512] f32, centers [C=10000, D=512] f32, labels [B] i32.
// Masked distmat keeps only dist[i, labels[i]]; masked zeros clamp to 1e-12.
// loss = (sum_i clamp(||x_i - c_{l_i}||^2, 1e-12, 1e12) + B*(C-1)*1e-12) / (B*C) / B

constexpr int B = 4096;
constexpr int C = 10000;
constexpr int D = 512;
constexpr int BLOCKS  = 256;   // 16 rows per block
constexpr int THREADS = 1024;  // 16 waves per block, one wave per row

__global__ void __launch_bounds__(1024) center_loss_fused(
    const float* __restrict__ x, const float* __restrict__ centers,
    const int* __restrict__ labels, float* __restrict__ out,
    double* __restrict__ partials) {
  const int wave = threadIdx.x >> 6;
  const int lane = threadIdx.x & 63;
  const int row  = blockIdx.x * 16 + wave;

  // --- per-row squared distance: one wave per row, float4 coalesced loads ---
  const int lbl = labels[row];
  const float4* xr = reinterpret_cast<const float4*>(x)       + (size_t)row * (D / 4);
  const float4* cr = reinterpret_cast<const float4*>(centers) + (size_t)lbl * (D / 4);

  float acc = 0.f;
#pragma unroll
  for (int j = 0; j < (D / 4) / 64; ++j) {   // 2 iterations, 2KB/wave contiguous
    const float4 a = xr[lane + j * 64];
    const float4 b = cr[lane + j * 64];
    const float d0 = a.x - b.x, d1 = a.y - b.y, d2 = a.z - b.z, d3 = a.w - b.w;
    acc = fmaf(d0, d0, fmaf(d1, d1, fmaf(d2, d2, fmaf(d3, d3, acc))));
  }
#pragma unroll
  for (int off = 32; off; off >>= 1) acc += __shfl_down(acc, off, 64);

  // --- block partial: sum of this block's 16 clamped row distances (f64) ---
  __shared__ double lds[16];
  if (lane == 0) lds[wave] = (double)fminf(fmaxf(acc, 1e-12f), 1e12f);
  __syncthreads();
  if (threadIdx.x == 0) {
    double s = 0.0;
#pragma unroll
    for (int w = 0; w < 16; ++w) s += lds[w];
    partials[blockIdx.x] = s;
  }

  cg::this_grid().sync();

  // --- final reduce: one wave of block 0 reads 256 partials ---
  if (blockIdx.x == 0 && threadIdx.x < 64) {
    double s = 0.0;
#pragma unroll
    for (int j = 0; j < BLOCKS / 64; ++j)    // 4 per lane
      s += partials[threadIdx.x + j * 64];
#pragma unroll
    for (int off = 32; off; off >>= 1) s += __shfl_down(s, off, 64);
    if (threadIdx.x == 0) {
      s += (double)B * (double)(C - 1) * 1e-12;            // clamped masked zeros
      out[0] = (float)(s / ((double)B * (double)C * (double)B));
    }
  }
}

extern "C" void kernel_launch(void* const* d_in, const int* in_sizes, int n_in,
                              void* d_out, int out_size, void* d_ws, size_t ws_size,
                              hipStream_t stream) {
  const float* x       = (const float*)d_in[0];
  const float* centers = (const float*)d_in[1];
  const int*   labels  = (const int*)d_in[2];
  float*  out      = (float*)d_out;
  double* partials = (double*)d_ws;   // 256 doubles

  void* args[] = {(void*)&x, (void*)&centers, (void*)&labels, (void*)&out, (void*)&partials};
  hipLaunchCooperativeKernel((void*)center_loss_fused, dim3(BLOCKS), dim3(THREADS),
                             args, 0, stream);
}

// Round 5
// 79.770 us; speedup vs baseline: 1.3294x; 1.3294x over previous
//
#include <hip/hip_runtime.h>

// CenterLoss: x [B=4096, D=512] f32, centers [C=10000, D=512] f32, labels [B] i32.
// Masked distmat keeps only dist[i, labels[i]]; masked zeros clamp to 1e-12.
// loss = (sum_i clamp(||x_i - c_{l_i}||^2, 1e-12, 1e12) + B*(C-1)*1e-12) / (B*C) / B
//
// Single-pass: per-wave row distance -> per-block f64 partial -> one f64
// atomicAdd per block -> last block (ticket counter) finalizes. No second
// dispatch, no cooperative launch (round-2 showed grid.sync costs +33us).

constexpr int B = 4096;
constexpr int C = 10000;
constexpr int D = 512;
constexpr int BLOCKS  = 256;   // 16 rows per block, one wave per row
constexpr int THREADS = 1024;

struct WsHdr {          // lives at start of d_ws, zeroed by hipMemsetAsync
  double acc;           // global f64 accumulator
  unsigned int ticket;  // arrival counter
  unsigned int pad;
};

__global__ void __launch_bounds__(1024) center_loss_onepass(
    const float* __restrict__ x, const float* __restrict__ centers,
    const int* __restrict__ labels, float* __restrict__ out,
    WsHdr* __restrict__ hdr) {
  const int wave = threadIdx.x >> 6;
  const int lane = threadIdx.x & 63;
  const int row  = blockIdx.x * 16 + wave;

  // --- per-row squared distance: one wave per row, float4 coalesced loads ---
  const int lbl = labels[row];
  const float4* xr = reinterpret_cast<const float4*>(x)       + (size_t)row * (D / 4);
  const float4* cr = reinterpret_cast<const float4*>(centers) + (size_t)lbl * (D / 4);

  float acc = 0.f;
#pragma unroll
  for (int j = 0; j < (D / 4) / 64; ++j) {   // 2 iterations, 2KB/wave contiguous
    const float4 a = xr[lane + j * 64];
    const float4 b = cr[lane + j * 64];
    const float d0 = a.x - b.x, d1 = a.y - b.y, d2 = a.z - b.z, d3 = a.w - b.w;
    acc = fmaf(d0, d0, fmaf(d1, d1, fmaf(d2, d2, fmaf(d3, d3, acc))));
  }
#pragma unroll
  for (int off = 32; off; off >>= 1) acc += __shfl_down(acc, off, 64);

  // --- block partial: sum of this block's 16 clamped row distances (f64) ---
  __shared__ double lds[16];
  if (lane == 0) lds[wave] = (double)fminf(fmaxf(acc, 1e-12f), 1e12f);
  __syncthreads();

  if (threadIdx.x == 0) {
    double s = 0.0;
#pragma unroll
    for (int w = 0; w < 16; ++w) s += lds[w];
    atomicAdd(&hdr->acc, s);                  // device-scope f64 atomic
    __threadfence();
    const unsigned int prev = atomicAdd(&hdr->ticket, 1u);
    if (prev == BLOCKS - 1) {
      // last block: all acc-adds are globally visible (fence + RMW ordering)
      double tot = atomicAdd(&hdr->acc, 0.0); // atomic read for coherence
      tot += (double)B * (double)(C - 1) * 1e-12;   // clamped masked zeros
      out[0] = (float)(tot / ((double)B * (double)C * (double)B));
    }
  }
}

extern "C" void kernel_launch(void* const* d_in, const int* in_sizes, int n_in,
                              void* d_out, int out_size, void* d_ws, size_t ws_size,
                              hipStream_t stream) {
  const float* x       = (const float*)d_in[0];
  const float* centers = (const float*)d_in[1];
  const int*   labels  = (const int*)d_in[2];
  float* out = (float*)d_out;
  WsHdr* hdr = (WsHdr*)d_ws;

  hipMemsetAsync(hdr, 0, sizeof(WsHdr), stream);   // zero acc + ticket
  center_loss_onepass<<<BLOCKS, THREADS, 0, stream>>>(x, centers, labels, out, hdr);
}

// Round 7
// 73.673 us; speedup vs baseline: 1.4394x; 1.0828x over previous
//
#include <hip/hip_runtime.h>

// CenterLoss: x [B=4096, D=512] f32, centers [C=10000, D=512] f32, labels [B] i32.
// Masked distmat keeps only dist[i, labels[i]]; masked zeros clamp to 1e-12.
// loss = (sum_i clamp(||x_i - c_{l_i}||^2, 1e-12, 1e12) + B*(C-1)*1e-12) / (B*C) / B
//
// Round-5 post-mortem: fused one-pass (atomics+ticket) = 79.8us, cooperative
// grid.sync = 106us, two-kernel = 72.9us. Two lean kernels win: launch/latency
// overhead dominates (real traffic ~15MB ~ 3us); keep both kernels minimal.

constexpr int B = 4096;
constexpr int C = 10000;
constexpr int D = 512;

// Kernel 1: one wave (64 lanes) per row, 4 waves per 256-thread block.
// Each lane: 2 float4 of x and of the gathered center row (2KB contiguous
// per wave -> fully coalesced). No LDS, no syncthreads; lane0 stores row dist.
__global__ void __launch_bounds__(256, 4) row_dist_kernel(
    const float* __restrict__ x, const float* __restrict__ centers,
    const int* __restrict__ labels, float* __restrict__ row_out) {
  const int row  = (blockIdx.x << 2) + (threadIdx.x >> 6);
  const int lane = threadIdx.x & 63;

  const int lbl = labels[row];
  const float4* xr = reinterpret_cast<const float4*>(x)       + (size_t)row * (D / 4);
  const float4* cr = reinterpret_cast<const float4*>(centers) + (size_t)lbl * (D / 4);

  float acc = 0.f;
#pragma unroll
  for (int j = 0; j < (D / 4) / 64; ++j) {   // 2 iterations
    const float4 a = xr[lane + j * 64];
    const float4 b = cr[lane + j * 64];
    const float d0 = a.x - b.x, d1 = a.y - b.y, d2 = a.z - b.z, d3 = a.w - b.w;
    acc = fmaf(d0, d0, fmaf(d1, d1, fmaf(d2, d2, fmaf(d3, d3, acc))));
  }
#pragma unroll
  for (int off = 32; off; off >>= 1) acc += __shfl_down(acc, off, 64);

  if (lane == 0)
    row_out[row] = fminf(fmaxf(acc, 1e-12f), 1e12f);   // faithful clamp
}

// Kernel 2: ONE wave. 4096 f32 = 1024 float4; lane reads float4[lane + j*64],
// 16 fully-coalesced iterations, f64 accumulate, shuffle reduce. No LDS.
__global__ void __launch_bounds__(64) reduce_kernel(
    const float* __restrict__ row_dist, float* __restrict__ out) {
  const int lane = threadIdx.x;
  const float4* rd = reinterpret_cast<const float4*>(row_dist);

  double s = 0.0;
#pragma unroll
  for (int j = 0; j < (B / 4) / 64; ++j) {   // 16 iterations
    const float4 v = rd[lane + j * 64];
    s += (double)v.x + (double)v.y + (double)v.z + (double)v.w;
  }
#pragma unroll
  for (int off = 32; off; off >>= 1) s += __shfl_down(s, off, 64);

  if (lane == 0) {
    s += (double)B * (double)(C - 1) * 1e-12;          // clamped masked zeros
    out[0] = (float)(s / ((double)B * (double)C * (double)B));
  }
}

extern "C" void kernel_launch(void* const* d_in, const int* in_sizes, int n_in,
                              void* d_out, int out_size, void* d_ws, size_t ws_size,
                              hipStream_t stream) {
  const float* x       = (const float*)d_in[0];
  const float* centers = (const float*)d_in[1];
  const int*   labels  = (const int*)d_in[2];
  float* out = (float*)d_out;
  float* ws  = (float*)d_ws;   // 4096 floats of per-row distances

  row_dist_kernel<<<B / 4, 256, 0, stream>>>(x, centers, labels, ws);
  reduce_kernel<<<1, 64, 0, stream>>>(ws, out);
}